// Round 1
// baseline (120.306 us; speedup 1.0000x reference)
//
#include <hip/hip_runtime.h>

// ModelInverse: invert monotone MLP CDF F(x) for 2M targets.
// Strategy: F is sample-independent -> tabulate A(x) on 2^16+1 grid,
// build inverse table G on a uniform z-grid, then per-sample lerp lookup.
//
// ws layout (floats): WE2[4096] | WE1[64] | WE3[64] | T[65537] | G[65537]
// total = 135298 floats = 541192 bytes.

#define MONO 1e-3f
#define MLOG2 16
#define MSZ (1 << MLOG2)   // forward table: T[0..MSZ]
#define KSZ MSZ            // inverse table: G[0..KSZ]

#define WS_WE2 0
#define WS_WE1 4096
#define WS_WE3 (4096 + 64)
#define WS_T   (4096 + 128)
#define WS_G   (WS_T + MSZ + 1)

__device__ __forceinline__ float sigmoidf_(float t) {
    return 1.0f / (1.0f + expf(-t));
}

__global__ void exp_weights_kernel(const float* __restrict__ pw1,
                                   const float* __restrict__ pw2,
                                   const float* __restrict__ pw3,
                                   float* __restrict__ ws) {
    int i = blockIdx.x * blockDim.x + threadIdx.x;
    if (i < 4096) ws[WS_WE2 + i] = expf(pw2[i]);
    if (i < 64) {
        ws[WS_WE1 + i] = expf(pw1[i]);  // pre_w1 is (64,1) flat
        ws[WS_WE3 + i] = expf(pw3[i]);  // pre_w3 is (1,64) flat
    }
}

// T[j] = A(j/MSZ) = sigmoid(w3 . sigmoid(W2 . sigmoid(x*w1 + b1) + b2) + b3) + MONO*x
// Weights are wave-uniform -> scalar loads; h1 kept in VGPRs via full unroll.
__global__ void build_table_kernel(const float* __restrict__ b1,
                                   const float* __restrict__ b2,
                                   const float* __restrict__ b3,
                                   const float* __restrict__ ws,
                                   float* __restrict__ T) {
    int j = blockIdx.x * blockDim.x + threadIdx.x;
    if (j > MSZ) return;
    const float* __restrict__ WE2 = ws + WS_WE2;
    const float* __restrict__ WE1 = ws + WS_WE1;
    const float* __restrict__ WE3 = ws + WS_WE3;

    float x = (float)j * (1.0f / (float)MSZ);

    float h1[64];
#pragma unroll
    for (int k = 0; k < 64; ++k)
        h1[k] = sigmoidf_(fmaf(x, WE1[k], b1[k]));

    float acc3 = b3[0];
    for (int i = 0; i < 64; ++i) {   // i is uniform -> WE2 row via s_load
        float acc = b2[i];
        const float* __restrict__ wrow = WE2 + i * 64;
#pragma unroll
        for (int jj = 0; jj < 64; ++jj)
            acc = fmaf(wrow[jj], h1[jj], acc);
        acc3 = fmaf(WE3[i], sigmoidf_(acc), acc3);
    }
    T[j] = sigmoidf_(acc3) + MONO * x;
}

// G[k] = x such that F(x) = k/KSZ, via binary search in T + in-cell lerp.
__global__ void invert_table_kernel(const float* __restrict__ T,
                                    float* __restrict__ G) {
    int k = blockIdx.x * blockDim.x + threadIdx.x;
    if (k > KSZ) return;
    float a0 = T[0];
    float a1 = T[MSZ];
    float zt = fmaf((float)k * (1.0f / (float)KSZ), a1 - a0, a0);

    int lo = 0;
#pragma unroll
    for (int s = MSZ >> 1; s >= 1; s >>= 1) {
        int cand = lo + s;             // cand <= MSZ-1 always
        if (T[cand] <= zt) lo = cand;
    }
    // lo = max{ j in [0, MSZ-1] : T[j] <= zt } (monotone T)
    float tl = T[lo];
    float th = T[lo + 1];
    float d = th - tl;
    float t = (d > 1e-30f) ? (zt - tl) / d : 0.5f;  // guard sub-ulp flat cells
    t = fminf(fmaxf(t, 0.0f), 1.0f);
    G[k] = ((float)lo + t) * (1.0f / (float)MSZ);
}

__global__ void apply_kernel(const float* __restrict__ z,
                             const float* __restrict__ G,
                             float* __restrict__ out, int n) {
    int i = blockIdx.x * blockDim.x + threadIdx.x;
    if (i >= n) return;
    float u = z[i] * (float)KSZ;
    u = fminf(fmaxf(u, 0.0f), (float)KSZ);
    int k = (int)u;
    if (k > KSZ - 1) k = KSZ - 1;
    float frac = u - (float)k;
    float g0 = G[k];
    float g1 = G[k + 1];
    out[i] = fmaf(frac, g1 - g0, g0);
}

extern "C" void kernel_launch(void* const* d_in, const int* in_sizes, int n_in,
                              void* d_out, int out_size, void* d_ws, size_t ws_size,
                              hipStream_t stream) {
    const float* z   = (const float*)d_in[0];
    const float* pw1 = (const float*)d_in[1];
    const float* b1  = (const float*)d_in[2];
    const float* pw2 = (const float*)d_in[3];
    const float* b2  = (const float*)d_in[4];
    const float* pw3 = (const float*)d_in[5];
    const float* b3  = (const float*)d_in[6];
    float* out = (float*)d_out;
    float* ws  = (float*)d_ws;
    int n = in_sizes[0];

    exp_weights_kernel<<<16, 256, 0, stream>>>(pw1, pw2, pw3, ws);
    build_table_kernel<<<(MSZ + 1 + 255) / 256, 256, 0, stream>>>(
        b1, b2, b3, ws, ws + WS_T);
    invert_table_kernel<<<(KSZ + 1 + 255) / 256, 256, 0, stream>>>(
        ws + WS_T, ws + WS_G);
    apply_kernel<<<(n + 255) / 256, 256, 0, stream>>>(z, ws + WS_G, out, n);
}